// Round 4
// baseline (25380.830 us; speedup 1.0000x reference)
//
#include <hip/hip_runtime.h>
#include <hip/hip_bf16.h>

// TTS: embed -> BiLSTM encoder -> K/V proj -> 1000-step autoregressive decode.
// ALL inputs/outputs are FP32 (reference uses jnp.float32). Decode weights are
// staged to bf16 once per launch (fp32 accumulate) to keep the per-XCD working
// set L2-resident. Decode: h(256/b)-recurrence, fused W2m=W2@Wmel, Wqh=Wq@Wmel
// (Wqh kept fp32 for logit accuracy); attended via per-head Wo partials +
// gate-side reduce. Persistent kernels, agent-scope group barriers,
// 2 barriers/decode step. ws use: 3.2 MB; bulk prep scratch in d_out.

typedef unsigned short u16;
typedef unsigned int   u32;
#define DI __device__ __forceinline__

// ---- ws layout (bytes) ---- total ~3.2MB
static constexpr size_t WS_BAR   = 0;              // int[4096] 16KB
static constexpr size_t WS_HBUF  = 16*1024;        // fp32 [16][256] 16KB
static constexpr size_t WS_PROBS = 32*1024;        // fp32 [16][8][128] 64KB
static constexpr size_t WS_BIAS  = 96*1024;        // fp32 bqp[512]|bg0[1024]|bgp[1024]
static constexpr size_t WS_ATTB  = 112*1024;       // fp32 [16][8][512] 256KB
static constexpr size_t WS_W2M   = 368*1024;       // bf16 [1024][256] 512KB
static constexpr size_t WS_WQH   = 880*1024;       // fp32 [512][256]  512KB
static constexpr size_t WS_WOB   = 1392*1024;      // bf16 [512][512]  512KB
static constexpr size_t WS_W1B   = 1904*1024;      // bf16 [1024][512] 1MB
static constexpr size_t WS_WMB   = 2928*1024;      // bf16 [512][256]  256KB -> 3184KB

// ---- d_out scratch (bytes; d_out = 8,210,048 fp32 = 32.84MB) ----
// xw/enc/Whh dead before first decode write. K/V bf16 live in each batch's own
// mel region (first 256KB of batch b's 2.048MB) — ordered by group barriers.
static constexpr size_t OS_XWF = 0;                        // fp32 [2048][1024] 8MB
static constexpr size_t OS_XWB = (size_t)8*1024*1024;      // 8MB
static constexpr size_t OS_ENC = (size_t)16*1024*1024;     // fp32 [2048][512] 4MB
static constexpr size_t OS_WHF = (size_t)20*1024*1024;     // bf16 [1024][256] 512KB
static constexpr size_t OS_WHB = OS_WHF + 512*1024;        // 512KB -> 21MB

DI float bf2f(u16 u){ union{u32 i; float f;} v; v.i = ((u32)u)<<16; return v.f; }
DI u16 f2bf(float f){ union{float f; u32 i;} v; v.f = f;
  u32 r = v.i + 0x7fffu + ((v.i>>16)&1u); return (u16)(r>>16); }
DI float2 bf2x(u32 u){ union{u32 i; float f;} a,b; a.i = u<<16; b.i = u & 0xffff0000u;
  float2 r; r.x = a.f; r.y = b.f; return r; }
DI float dot8(uint4 wv, float4 a, float4 b){   // bf16 weights x fp32 acts
  float2 w0 = bf2x(wv.x), w1 = bf2x(wv.y), w2 = bf2x(wv.z), w3 = bf2x(wv.w);
  return w0.x*a.x + w0.y*a.y + w1.x*a.z + w1.y*a.w
       + w2.x*b.x + w2.y*b.y + w3.x*b.z + w3.y*b.w;
}
DI float dot8f(float4 wa, float4 wb, float4 a, float4 b){   // fp32 x fp32
  return wa.x*a.x + wa.y*a.y + wa.z*a.z + wa.w*a.w
       + wb.x*b.x + wb.y*b.y + wb.z*b.z + wb.w*b.w;
}
DI float sigm(float x){ return 1.f/(1.f + __expf(-x)); }

DI void bar_arrive(int* bar, int target, int t){
  __syncthreads();
  if (threadIdx.x == 0){
    int a = __hip_atomic_fetch_add(&bar[0], 1, __ATOMIC_ACQ_REL, __HIP_MEMORY_SCOPE_AGENT);
    if (a == target-1){
      __hip_atomic_store(&bar[0], 0, __ATOMIC_RELAXED, __HIP_MEMORY_SCOPE_AGENT);
      __hip_atomic_store(&bar[1], t, __ATOMIC_RELEASE, __HIP_MEMORY_SCOPE_AGENT);
    }
  }
}
DI void bar_wait(int* bar, int t){
  if (threadIdx.x == 0){
    while (__hip_atomic_load(&bar[1], __ATOMIC_RELAXED, __HIP_MEMORY_SCOPE_AGENT) < t)
      __builtin_amdgcn_s_sleep(2);
    (void)__hip_atomic_load(&bar[1], __ATOMIC_ACQUIRE, __HIP_MEMORY_SCOPE_AGENT);
  }
  __syncthreads();
}

__global__ __launch_bounds__(256) void k_init(int* bars, float* hbuf){
  int i = threadIdx.x;
  for (int k = i; k < 4096; k += 256) bars[k] = 0;
  for (int k = i; k < 4096; k += 256) hbuf[k] = 0.f;
}

// fused embed + x@Wih.T + biases -> xw fp32. 2048 blocks.
__global__ __launch_bounds__(256) void k_xw(
    const int* __restrict__ tok, const int* __restrict__ spk,
    const float* __restrict__ et, const float* __restrict__ es,
    const float* __restrict__ WihF, const float* __restrict__ bihF, const float* __restrict__ bhhF,
    const float* __restrict__ WihB, const float* __restrict__ bihB, const float* __restrict__ bhhB,
    float* __restrict__ xwf, float* __restrict__ xwb){
  const int tid = threadIdx.x, bi = blockIdx.x;
  const int dir = bi & 1, jc = (bi >> 1) & 3, btg = bi >> 3;
  const int j = jc*256 + tid;
  const float* W = (dir ? WihB : WihF) + j*256;
  const float bias = (dir ? bihB : bihF)[j] + (dir ? bhhB : bhhF)[j];
  float* xw = dir ? xwb : xwf;

  __shared__ __align__(16) float lx[8][256];
  #pragma unroll
  for (int r = 0; r < 8; ++r){
    const int bt = btg*8 + r;
    lx[r][tid] = et[tok[bt]*256 + tid] + es[spk[bt>>7]*256 + tid];
  }
  __syncthreads();

  float acc[8];
  #pragma unroll
  for (int k2 = 0; k2 < 8; ++k2) acc[k2] = bias;
  for (int h = 0; h < 256; h += 8){
    float4 w0 = *(const float4*)(W + h);
    float4 w1 = *(const float4*)(W + h + 4);
    #pragma unroll
    for (int k2 = 0; k2 < 8; ++k2)
      acc[k2] += dot8f(w0, w1, *(const float4*)(&lx[k2][h]), *(const float4*)(&lx[k2][h+4]));
  }
  #pragma unroll
  for (int k2 = 0; k2 < 8; ++k2) xw[(btg*8 + k2)*1024 + j] = acc[k2];
}

// bf16 conversions: Wo, W1=decW[:, :512], Wmel, WhhF, WhhB. 5632 blocks x 256.
__global__ __launch_bounds__(256) void k_cvt(
    const float* __restrict__ Wo, const float* __restrict__ decW,
    const float* __restrict__ Wmel,
    const float* __restrict__ WhhF, const float* __restrict__ WhhB,
    u16* __restrict__ Wob, u16* __restrict__ W1b, u16* __restrict__ Wmelb,
    u16* __restrict__ WhFb, u16* __restrict__ WhBb){
  const int idx = blockIdx.x*256 + threadIdx.x;
  if (idx < 262144){
    Wob[idx] = f2bf(Wo[idx]);
  } else if (idx < 786432){
    const int i = idx - 262144;
    W1b[i] = f2bf(decW[(i >> 9)*1024 + (i & 511)]);
  } else if (idx < 917504){
    const int i = idx - 786432;
    Wmelb[i] = f2bf(Wmel[i]);
  } else if (idx < 1179648){
    const int i = idx - 917504;
    WhFb[i] = f2bf(WhhF[i]);
  } else {
    const int i = idx - 1179648;
    WhBb[i] = f2bf(WhhB[i]);
  }
}

// W2m = W2@Wmel -> bf16 [1024,256]; Wqh = Wq@Wmel -> fp32 [512,256]. 384 blocks.
__global__ __launch_bounds__(256) void k_fuse(
    const float* __restrict__ decW, const float* __restrict__ Wmel, const float* __restrict__ Wq,
    u16* __restrict__ W2m, float* __restrict__ Wqh){
  const int tid = threadIdx.x, blk = blockIdx.x;
  float acc[4] = {0.f,0.f,0.f,0.f};
  const int h = tid;
  if (blk < 256){
    const int g0 = blk*4;
    for (int m = 0; m < 512; ++m){
      float wm = Wmel[m*256 + h];
      #pragma unroll
      for (int i2 = 0; i2 < 4; ++i2) acc[i2] += decW[(g0+i2)*1024 + 512 + m] * wm;
    }
    #pragma unroll
    for (int i2 = 0; i2 < 4; ++i2) W2m[(g0+i2)*256 + h] = f2bf(acc[i2]);
  } else {
    const int j0 = (blk - 256)*4;
    for (int e = 0; e < 512; ++e){
      float wm = Wmel[e*256 + h];
      #pragma unroll
      for (int i2 = 0; i2 < 4; ++i2) acc[i2] += Wq[(j0+i2)*512 + e] * wm;
    }
    #pragma unroll
    for (int i2 = 0; i2 < 4; ++i2) Wqh[(j0+i2)*256 + h] = acc[i2];
  }
}

__global__ __launch_bounds__(256) void k_bias(
    const float* __restrict__ Wq, const float* __restrict__ bq, const float* __restrict__ bmel,
    const float* __restrict__ decW, const float* __restrict__ bo,
    const float* __restrict__ bih, const float* __restrict__ bhh, float* __restrict__ biasws){
  const int o = blockIdx.x*256 + threadIdx.x;   // 6 blocks -> 1536
  if (o < 512){
    float s = bq[o];
    for (int e = 0; e < 512; ++e) s += Wq[o*512 + e] * bmel[e];
    biasws[o] = s;                               // bq' = Wq@bmel + bq
  } else {
    const int gr = o - 512;
    float s1 = bih[gr] + bhh[gr];
    for (int jj = 0; jj < 512; ++jj) s1 += decW[gr*1024 + jj] * bo[jj];
    biasws[512 + gr] = s1;                       // bg0 = W1@bo + bih + bhh
    float s2 = s1;
    for (int m = 0; m < 512; ++m) s2 += decW[gr*1024 + 512 + m] * bmel[m];
    biasws[1536 + gr] = s2;                      // bg' = bg0 + W2@bmel
  }
}

// persistent BiLSTM encoder: 32 groups (dir,b) x 8 WGs x 128 thr. Whh bf16 staged.
__global__ __launch_bounds__(128) void k_enc(
    const float* __restrict__ xwf, const float* __restrict__ xwb,
    const u16* __restrict__ WhFb, const u16* __restrict__ WhBb,
    float* __restrict__ enc, int* bars){
  const int tid = threadIdx.x;
  const int xcd = blockIdx.x & 7, sl = blockIdx.x >> 3;
  const int grp = xcd*4 + (sl >> 3);
  const int w = sl & 7;
  const int dir = grp & 1, b = grp >> 1;
  int* bar = bars + (16 + grp)*64;
  const u16* Whh = dir ? WhBb : WhFb;
  const float* xw = dir ? xwb : xwf;
  const int q = tid >> 5, ii = tid & 31;
  const int j = q*256 + w*32 + ii;
  const u16* wr = Whh + j*256;

  __shared__ float l_g[4][32];
  __shared__ float l_c[32];
  if (tid < 32) l_c[tid] = 0.f;
  __syncthreads();

  for (int it = 0; it < 128; ++it){
    const int ts = dir ? (127 - it) : it;
    float acc = xw[(b*128 + ts)*1024 + j];
    if (it > 0){
      const int tp = dir ? (ts + 1) : (ts - 1);
      const float* hp = enc + (b*128 + tp)*512 + dir*256;
      #pragma unroll 4
      for (int k = 0; k < 256; k += 8)
        acc += dot8(*(const uint4*)(wr + k), *(const float4*)(hp + k), *(const float4*)(hp + k + 4));
    }
    l_g[q][ii] = acc;
    __syncthreads();
    if (tid < 32){
      float ig = l_g[0][tid], fg = l_g[1][tid], gg = l_g[2][tid], og = l_g[3][tid];
      float c = sigm(fg)*l_c[tid] + sigm(ig)*tanhf(gg);
      l_c[tid] = c;
      enc[(b*128 + ts)*512 + dir*256 + w*32 + tid] = sigm(og)*tanhf(c);
    }
    bar_arrive(bar, 8, it+1);
    bar_wait(bar, it+1);
  }
}

// K,V projections -> bf16, stored in per-batch slot at outf + b*512000.
// slot layout (u16): K[head][t][d] (65536) then V[head][d][t] (65536). 1024 blocks.
__global__ __launch_bounds__(256) void k_proj(
    const float* __restrict__ enc,
    const float* __restrict__ Wk, const float* __restrict__ bk,
    const float* __restrict__ Wv, const float* __restrict__ bv,
    float* outf){
  const int tid = threadIdx.x, x = blockIdx.x;
  const int role = x & 1, dc = (x >> 1) & 1, btg = x >> 2;
  const int row = dc*256 + tid;
  const float* W = (role ? Wv : Wk) + row*512;
  const float bias = (role ? bv : bk)[row];
  float acc[8];
  #pragma unroll
  for (int k2 = 0; k2 < 8; ++k2) acc[k2] = bias;
  for (int e = 0; e < 512; e += 8){
    float4 wa = *(const float4*)(W + e);
    float4 wb = *(const float4*)(W + e + 4);
    #pragma unroll
    for (int k2 = 0; k2 < 8; ++k2){
      const float* ep = enc + (btg*8 + k2)*512 + e;
      acc[k2] += dot8f(wa, wb, *(const float4*)(ep), *(const float4*)(ep + 4));
    }
  }
  const int head = row >> 6, dd = row & 63;
  #pragma unroll
  for (int k2 = 0; k2 < 8; ++k2){
    const int bt = btg*8 + k2, b = bt >> 7, ts = bt & 127;
    u16* kv = (u16*)(outf + (size_t)b*512000);
    if (role == 0) kv[head*8192 + ts*64 + dd] = f2bf(acc[k2]);
    else           kv[65536 + head*8192 + dd*128 + ts] = f2bf(acc[k2]);
  }
}

// persistent decoder: 8 groups (b-pair) x 32 WGs x 256 thr; 2 barriers/step.
__global__ __launch_bounds__(256) void k_decode(
    const u16* __restrict__ Wmelb, const float* __restrict__ bmel,
    const float* __restrict__ Wstop, const float* __restrict__ bstop,
    const float* __restrict__ bq,
    const u16* __restrict__ Wob, const u16* __restrict__ W1b,
    const u16* __restrict__ W2m, const float* __restrict__ Wqh,
    const float* __restrict__ biasws,
    float* __restrict__ hbuf, float* __restrict__ attb, float* __restrict__ probs,
    int* bars, float* out){   // out NOT restrict: K/V slots alias mel region
  const int tid = threadIdx.x;
  const int g = blockIdx.x & 7, slot = blockIdx.x >> 3;
  const int b0 = g*2;
  int* barA = bars + g*64;
  int* barB = bars + (8+g)*64;
  const float* bqp = biasws;
  const float* bg0 = biasws + 512;
  const float* bgp = biasws + 1536;
  float* out_mel  = out;
  float* out_stop = out + 8192000;
  float* out_attn = out + 8208000;

  // K row stride 72 u16, V row stride 136: balanced b128 LDS reads.
  __shared__ __align__(16) u16 lK[128*72];
  __shared__ __align__(16) u16 lV[64*136];
  __shared__ __align__(16) float l_t4[4][64];
  __shared__ __align__(16) float l_q[64];
  __shared__ __align__(16) float l_p[128];
  __shared__ __align__(16) float l_ctx[64];
  __shared__ float l_r[4];
  __shared__ __align__(16) float l_att[1024];
  __shared__ float l_w2[256];
  __shared__ float l_gc[256];
  __shared__ float l_gate[128];

  if (slot < 16){
    // ---------------- attention slot (b,head) ----------------
    const int b = b0 + (slot >> 3), head = slot & 7;
    const int d = tid & 63, kq = tid >> 6;
    {  // prelude: K,V -> LDS. Reads scratch inside THIS batch's mel region,
       // which this group's gate blocks first overwrite only after barB(1).
      const u16* kv = (const u16*)(out + (size_t)b*512000);
      const u16* gK = kv + head*8192;
      const u16* gV = kv + 65536 + head*8192;
      for (int i = tid; i < 1024; i += 256){
        const int r = i >> 3, c = i & 7;
        *(uint4*)(lK + r*72 + c*8) = *(const uint4*)(gK + r*64 + c*8);
      }
      for (int i = tid; i < 1024; i += 256){
        const int r = i >> 4, c = i & 15;
        *(uint4*)(lV + r*136 + c*8) = *(const uint4*)(gV + r*128 + c*8);
      }
      __syncthreads();
    }
    const float* wqr = Wqh + (head*64 + d)*256 + kq*64;
    const float* hpq = hbuf + b*256 + kq*64;
    for (int t = 0; t < 1000; ++t){
      float qp = 0.f;
      if (t > 0){
        #pragma unroll
        for (int k = 0; k < 64; k += 8)
          qp += dot8f(*(const float4*)(wqr + k), *(const float4*)(wqr + k + 4),
                      *(const float4*)(hpq + k), *(const float4*)(hpq + k + 4));
      }
      l_t4[kq][d] = qp;
      __syncthreads();
      if (tid < 64){
        float qq = l_t4[0][tid] + l_t4[1][tid] + l_t4[2][tid] + l_t4[3][tid];
        qq += (t == 0) ? bq[head*64 + tid] : bqp[head*64 + tid];
        l_q[tid] = qq;
      }
      __syncthreads();
      float s = 0.f;
      if (tid < 128){
        const u16* kr = lK + tid*72;
        #pragma unroll
        for (int k = 0; k < 64; k += 8)
          s += dot8(*(const uint4*)(kr + k), *(const float4*)(l_q + k), *(const float4*)(l_q + k + 4));
        s *= 0.125f;
        float m = s;
        #pragma unroll
        for (int off = 32; off; off >>= 1) m = fmaxf(m, __shfl_xor(m, off));
        if ((tid & 63) == 0) l_r[tid >> 6] = m;
      }
      __syncthreads();
      float p = 0.f;
      if (tid < 128){
        float M = fmaxf(l_r[0], l_r[1]);
        p = __expf(s - M);
        float ss = p;
        #pragma unroll
        for (int off = 32; off; off >>= 1) ss += __shfl_xor(ss, off);
        if ((tid & 63) == 0) l_r[2 + (tid >> 6)] = ss;
      }
      __syncthreads();
      if (tid < 128){
        p /= (l_r[2] + l_r[3]);
        l_p[tid] = p;
        if (t == 999) probs[(b*8 + head)*128 + tid] = p;
      }
      __syncthreads();
      {
        const u16* vr = lV + d*136 + kq*32;
        float cp = 0.f;
        #pragma unroll
        for (int k = 0; k < 32; k += 8)
          cp += dot8(*(const uint4*)(vr + k), *(const float4*)(l_p + kq*32 + k), *(const float4*)(l_p + kq*32 + k + 4));
        l_t4[kq][d] = cp;
      }
      __syncthreads();
      if (tid < 64)
        l_ctx[tid] = l_t4[0][tid] + l_t4[1][tid] + l_t4[2][tid] + l_t4[3][tid];
      __syncthreads();
      // attended partials (sans bo): attb[b][head][j] = Wo[j, head*64:+64] @ ctx
      for (int jj = tid; jj < 512; jj += 256){
        const u16* wo = Wob + jj*512 + head*64;
        float a = 0.f;
        #pragma unroll
        for (int k = 0; k < 64; k += 8)
          a += dot8(*(const uint4*)(wo + k), *(const float4*)(l_ctx + k), *(const float4*)(l_ctx + k + 4));
        attb[((size_t)(b*8 + head))*512 + jj] = a;
      }
      bar_arrive(barA, 32, t+1);   // publish partials; don't wait on A
      bar_wait(barB, t+1);         // wait for h_t
    }
    if (tid < 16){
      const int tt = (slot & 7)*16 + tid;
      float ssum = 0.f;
      #pragma unroll
      for (int h8 = 0; h8 < 8; ++h8) ssum += probs[(b*8 + h8)*128 + tt];
      out_attn[b*128 + tt] = ssum * 0.125f;
    }
  } else {
    // ---------------- gate slot ----------------
    const int w = slot - 16;
    const int bmb = b0 + (w >> 3);
    const int r0 = (w & 7)*64;
    const int rl = tid & 63, bl = (tid >> 6) & 1, half = tid >> 7;
    const int j = (rl >> 4)*256 + w*16 + (rl & 15);
    for (int t = 0; t <= 1000; ++t){
      if (t >= 1){
        const int r = r0 + (tid & 63), kq = tid >> 6;
        const u16* wr = Wmelb + r*256 + kq*64;
        const float* hp = hbuf + bmb*256 + kq*64;
        float mp = 0.f;
        #pragma unroll
        for (int k = 0; k < 64; k += 8)
          mp += dot8(*(const uint4*)(wr + k), *(const float4*)(hp + k), *(const float4*)(hp + k + 4));
        l_t4[kq][tid & 63] = mp;
        __syncthreads();
        if (tid < 64){
          float v = l_t4[0][tid] + l_t4[1][tid] + l_t4[2][tid] + l_t4[3][tid] + bmel[r0 + tid];
          out_mel[((size_t)bmb*1000 + (t-1))*512 + r0 + tid] = v;
        }
        if ((w & 7) == 0 && tid < 64){
          const float* hp2 = hbuf + bmb*256;
          float sp = 0.f;
          #pragma unroll
          for (int k2 = 0; k2 < 4; ++k2) sp += Wstop[tid*4 + k2] * hp2[tid*4 + k2];
          #pragma unroll
          for (int off = 32; off; off >>= 1) sp += __shfl_xor(sp, off);
          if (tid == 0) out_stop[bmb*1000 + (t-1)] = sp + bstop[0];
        }
      }
      if (t == 1000) break;
      {  // phase A: W2m @ h_{t-1} partials
        const u16* wr = W2m + j*256 + half*128;
        const float* hp = hbuf + (b0 + bl)*256 + half*128;
        float acc = 0.f;
        #pragma unroll 4
        for (int k = 0; k < 128; k += 8)
          acc += dot8(*(const uint4*)(wr + k), *(const float4*)(hp + k), *(const float4*)(hp + k + 4));
        l_w2[tid] = acc;
      }
      bar_arrive(barA, 32, t+1);
      bar_wait(barA, t+1);           // wait for attended partials
      // reduce partials over heads -> l_att[2][512]   (bo folded into bg0/bgp)
      for (int i = tid; i < 1024; i += 256){
        const int bl3 = i >> 9, jj = i & 511;
        const float* ap = attb + ((size_t)(b0 + bl3)*8)*512 + jj;
        float s2 = 0.f;
        #pragma unroll
        for (int h8 = 0; h8 < 8; ++h8) s2 += ap[h8*512];
        l_att[i] = s2;
      }
      __syncthreads();
      {  // phase B: gates = W1@attended + W2m@h + bias -> h_t
        const u16* wr = W1b + j*512 + half*256;
        const float* ap2 = l_att + bl*512 + half*256;
        float acc = 0.f;
        #pragma unroll 4
        for (int k = 0; k < 256; k += 8)
          acc += dot8(*(const uint4*)(wr + k), *(const float4*)(ap2 + k), *(const float4*)(ap2 + k + 4));
        l_gc[tid] = acc;
      }
      __syncthreads();
      if (tid < 128){
        const int rl2 = tid & 63, bl2 = tid >> 6;
        const int j2 = (rl2 >> 4)*256 + w*16 + (rl2 & 15);
        float gate = l_gc[bl2*64 + rl2] + l_gc[128 + bl2*64 + rl2]
                   + l_w2[bl2*64 + rl2] + l_w2[128 + bl2*64 + rl2]
                   + ((t == 0) ? bg0[j2] : bgp[j2]);
        l_gate[bl2*64 + rl2] = gate;
      }
      __syncthreads();
      if (tid < 32){
        const int il = tid & 15, bl2 = tid >> 4;
        float ig = l_gate[bl2*64 + il];
        float gg = l_gate[bl2*64 + 32 + il];
        float og = l_gate[bl2*64 + 48 + il];
        float c = sigm(ig)*tanhf(gg);              // decoder c_prev == 0 every step
        hbuf[(b0 + bl2)*256 + w*16 + il] = sigm(og)*tanhf(c);
      }
      bar_arrive(barB, 16, t+1);
      bar_wait(barB, t+1);
    }
  }
}

extern "C" void kernel_launch(void* const* d_in, const int* in_sizes, int n_in,
                              void* d_out, int out_size, void* d_ws, size_t ws_size,
                              hipStream_t stream){
  const int*   tok = (const int*)d_in[0];
  const int*   spk = (const int*)d_in[1];
  const float* emb_text = (const float*)d_in[2];
  const float* emb_spk  = (const float*)d_in[3];
  const float* WihF = (const float*)d_in[4];
  const float* WhhF = (const float*)d_in[5];
  const float* bihF = (const float*)d_in[6];
  const float* bhhF = (const float*)d_in[7];
  const float* WihB = (const float*)d_in[8];
  const float* WhhB = (const float*)d_in[9];
  const float* bihB = (const float*)d_in[10];
  const float* bhhB = (const float*)d_in[11];
  const float* Wq = (const float*)d_in[12];
  const float* bq = (const float*)d_in[13];
  const float* Wk = (const float*)d_in[14];
  const float* bk = (const float*)d_in[15];
  const float* Wv = (const float*)d_in[16];
  const float* bv = (const float*)d_in[17];
  const float* Wo = (const float*)d_in[18];
  const float* bo = (const float*)d_in[19];
  const float* decW = (const float*)d_in[20];
  /* d_in[21] dec_Whh dead (state re-zeroed every step) */
  const float* bih = (const float*)d_in[22];
  const float* bhh = (const float*)d_in[23];
  const float* Wmel = (const float*)d_in[24];
  const float* bmel = (const float*)d_in[25];
  const float* Wstop = (const float*)d_in[26];
  const float* bstop = (const float*)d_in[27];

  char* ws = (char*)d_ws;
  int*   bars   = (int*)(ws + WS_BAR);
  float* hbuf   = (float*)(ws + WS_HBUF);
  float* probs  = (float*)(ws + WS_PROBS);
  float* biasws = (float*)(ws + WS_BIAS);
  float* attb   = (float*)(ws + WS_ATTB);
  u16*   W2m    = (u16*)(ws + WS_W2M);
  float* Wqh    = (float*)(ws + WS_WQH);
  u16*   Wob    = (u16*)(ws + WS_WOB);
  u16*   W1b    = (u16*)(ws + WS_W1B);
  u16*   Wmelb  = (u16*)(ws + WS_WMB);

  char* ob = (char*)d_out;
  float* xwf  = (float*)(ob + OS_XWF);
  float* xwb  = (float*)(ob + OS_XWB);
  float* encS = (float*)(ob + OS_ENC);
  u16*   WhFb = (u16*)(ob + OS_WHF);
  u16*   WhBb = (u16*)(ob + OS_WHB);
  float* outf = (float*)d_out;

  k_init <<<1,    256, 0, stream>>>(bars, hbuf);
  k_xw   <<<2048, 256, 0, stream>>>(tok, spk, emb_text, emb_spk,
                                    WihF, bihF, bhhF, WihB, bihB, bhhB, xwf, xwb);
  k_cvt  <<<5632, 256, 0, stream>>>(Wo, decW, Wmel, WhhF, WhhB,
                                    Wob, W1b, Wmelb, WhFb, WhBb);
  k_enc  <<<256,  128, 0, stream>>>(xwf, xwb, WhFb, WhBb, encS, bars);
  k_fuse <<<384,  256, 0, stream>>>(decW, Wmel, Wq, W2m, Wqh);
  k_bias <<<6,    256, 0, stream>>>(Wq, bq, bmel, decW, bo, bih, bhh, biasws);
  k_proj <<<1024, 256, 0, stream>>>(encS, Wk, bk, Wv, bv, outf);
  k_decode<<<256, 256, 0, stream>>>(Wmelb, bmel, Wstop, bstop, bq,
                                    Wob, W1b, W2m, Wqh, biasws,
                                    hbuf, attb, probs, bars, outf);
}